// Round 11
// baseline (473.151 us; speedup 1.0000x reference)
//
#include <hip/hip_runtime.h>
#include <hip/hip_cooperative_groups.h>
#include <hip/hip_fp16.h>
#include <math.h>

namespace cg = cooperative_groups;

#define HID 64
#define IN_DIM 128
#define OUTC 8
#define TN 64        // nodes per block in dense/transform kernels
#define HPAD 72      // padded row stride (halfs) for dense LDS (K=64)
#define TPAD 136     // padded row stride (halfs) for transform LDS (K=128)

typedef _Float16 h2_t __attribute__((ext_vector_type(2)));

static __device__ __forceinline__ float fdot2f(unsigned a, unsigned b, float c){
#if __has_builtin(__builtin_amdgcn_fdot2)
  return __builtin_amdgcn_fdot2(*(h2_t*)&a, *(h2_t*)&b, c, false);
#else
  __half2 ha = *(__half2*)&a, hb = *(__half2*)&b;
  float2 fa = __half22float2(ha), fb = __half22float2(hb);
  return fmaf(fa.x, fb.x, fmaf(fa.y, fb.y, c));
#endif
}

// dot of 8 fp16 pairs with fp32 accumulate
static __device__ __forceinline__ float dot8h(uint4 a, uint4 b, float acc){
  acc = fdot2f(a.x, b.x, acc);
  acc = fdot2f(a.y, b.y, acc);
  acc = fdot2f(a.z, b.z, acc);
  acc = fdot2f(a.w, b.w, acc);
  return acc;
}

static __device__ __forceinline__ float dot4(float4 a, float4 b){
  return fmaf(a.x,b.x, fmaf(a.y,b.y, fmaf(a.z,b.z, a.w*b.w)));
}

static __device__ __forceinline__ uint2 pack4(float4 v){
  __half2 lo = __floats2half2_rn(v.x, v.y);
  __half2 hi = __floats2half2_rn(v.z, v.w);
  uint2 r; r.x = *(unsigned*)&lo; r.y = *(unsigned*)&hi; return r;
}

// ---------------------------------------------------------------------------
// Cooperative CSR build: zero + hist(+rank) + padded scan + fillpad + scatter
// in ONE dispatch with grid.sync() between phases. Grid: 256 blocks x 256 thr.
// ---------------------------------------------------------------------------
__global__ void k_build(const int* __restrict__ src, const int* __restrict__ dst,
                        const float* __restrict__ d, const float* __restrict__ wr,
                        const float* __restrict__ wi,
                        int* __restrict__ cnt, int* __restrict__ rank,
                        int* __restrict__ rowptr, int* __restrict__ partials,
                        uint2* __restrict__ eS, int N, int E, int nChunks){
  cg::grid_group grid = cg::this_grid();
  __shared__ int s[256];
  int tid = threadIdx.x, bid = blockIdx.x;
  int gtid = bid*256 + tid, GT = gridDim.x*256;

  // phase 1: zero counts
  for(int i=gtid; i<N; i+=GT) cnt[i]=0;
  grid.sync();

  // phase 2: histogram + per-edge rank
  for(int i=gtid; i<E; i+=GT) rank[i] = atomicAdd(&cnt[dst[i]], 1);
  grid.sync();

  // phase 3: per-chunk exclusive scan of padded counts (chunk == bid)
  if(bid < nChunks){
    int gid = bid*256 + tid;
    int v = (gid<N)? ((cnt[gid]+3)&~3) : 0;   // pad row to multiple of 4
    s[tid] = v; __syncthreads();
    #pragma unroll
    for(int off=1; off<256; off<<=1){
      int t = (tid>=off)? s[tid-off] : 0; __syncthreads();
      s[tid] += t; __syncthreads();
    }
    if(gid<N) rowptr[gid] = s[tid] - v;
    if(tid==255) partials[bid] = s[255];
  }
  grid.sync();

  // phase 4: block 0 scans the chunk sums; writes padded total to rowptr[N]
  if(bid==0){
    int v = (tid<nChunks)? partials[tid] : 0;
    s[tid] = v; __syncthreads();
    #pragma unroll
    for(int off=1; off<256; off<<=1){
      int t = (tid>=off)? s[tid-off] : 0; __syncthreads();
      s[tid] += t; __syncthreads();
    }
    if(tid<nChunks) partials[tid] = s[tid] - v;   // exclusive
    if(tid==nChunks-1) rowptr[N] = s[tid];        // total
  }
  grid.sync();

  // phase 5: add chunk bases
  if(bid < nChunks){
    int gid = bid*256 + tid;
    if(gid<N) rowptr[gid] += partials[bid];
  }
  grid.sync();

  // phase 6: fill pad slots + scatter edges (8B payload {src, half2(er,ei)})
  for(int n=gtid; n<N; n+=GT){
    int p = rowptr[n] + cnt[n], e = rowptr[n+1];
    for(; p<e; ++p) eS[p] = make_uint2(0u, 0u);
  }
  for(int i=gtid; i<E; i+=GT){
    int sv = src[i], t = dst[i];
    float dd = d[t]*d[sv];
    int p = rowptr[t] + rank[i];
    __half2 e2 = __floats2half2_rn(dd*wr[i], dd*wi[i]);
    uint2 q; q.x = (unsigned)sv; q.y = *(unsigned*)&e2;
    eS[p] = q;
  }
}

// h[N,128] -> hrhi[node*64+o] = half2(relu(h@Wr.T+br), relu(h@Wi.T+bi))
// fp16 LDS + fdot2; 256 thr = 16 o-lanes x 16 grps x 4 nodes; TN=64, K=128
__global__ __launch_bounds__(256, 3) void k_transform1(
    const float* __restrict__ h, const float* __restrict__ Wr, const float* __restrict__ br,
    const float* __restrict__ Wi, const float* __restrict__ bi,
    __half2* __restrict__ hrhi, int N){
  __shared__ __align__(16) __half sWrh[64*TPAD], sWih[64*TPAD], sXh[TN*TPAD];
  int tid = threadIdx.x;
  int o = tid & 15, grp = tid >> 4;
  int node0 = blockIdx.x*TN;
  #pragma unroll
  for(int t=0;t<8;t++){
    int f4 = tid + t*256; int row = f4>>5, kc = f4&31;
    *(uint2*)&sWrh[row*TPAD + kc*4] = pack4(*(const float4*)&Wr[row*IN_DIM + kc*4]);
    *(uint2*)&sWih[row*TPAD + kc*4] = pack4(*(const float4*)&Wi[row*IN_DIM + kc*4]);
  }
  #pragma unroll
  for(int t=0;t<8;t++){
    int f4 = tid + t*256; int nl = f4>>5, q = f4&31;
    int node = node0 + nl;
    float4 x = make_float4(0.f,0.f,0.f,0.f);
    if(node<N) x = *(const float4*)&h[node*IN_DIM + q*4];
    *(uint2*)&sXh[nl*TPAD + q*4] = pack4(x);
  }
  __syncthreads();
  float accR[4][4], accI[4][4];
  #pragma unroll
  for(int r=0;r<4;r++)
    #pragma unroll
    for(int m=0;m<4;m++){ accR[r][m]=0.f; accI[r][m]=0.f; }
  #pragma unroll 2
  for(int c=0;c<16;c++){
    uint4 wr4[4], wi4[4];
    #pragma unroll
    for(int r=0;r<4;r++){
      wr4[r] = *(const uint4*)&sWrh[(o+16*r)*TPAD + c*8];
      wi4[r] = *(const uint4*)&sWih[(o+16*r)*TPAD + c*8];
    }
    #pragma unroll
    for(int m=0;m<4;m++){
      uint4 x = *(const uint4*)&sXh[(grp*4+m)*TPAD + c*8];
      #pragma unroll
      for(int r=0;r<4;r++){
        accR[r][m] = dot8h(x, wr4[r], accR[r][m]);
        accI[r][m] = dot8h(x, wi4[r], accI[r][m]);
      }
    }
  }
  float brv[4], biv[4];
  #pragma unroll
  for(int r=0;r<4;r++){ brv[r]=br[o+16*r]; biv[r]=bi[o+16*r]; }
  #pragma unroll
  for(int m=0;m<4;m++){
    int node = node0 + grp*4 + m;
    if(node<N){
      #pragma unroll
      for(int r=0;r<4;r++){
        hrhi[node*HID + o + 16*r] =
          __floats2half2_rn(fmaxf(accR[r][m]+brv[r],0.f), fmaxf(accI[r][m]+biv[r],0.f));
      }
    }
  }
}

// CSR gather aggregation, 4 nodes per wave, 8 edges per iteration.
__global__ __launch_bounds__(256) void k_agg(
    const int* __restrict__ rowptr, const uint2* __restrict__ eS,
    const __half2* __restrict__ hrhi, float* __restrict__ zrzi, int N){
  int lane = threadIdx.x & 63;
  int wid = blockIdx.x*(blockDim.x>>6) + (threadIdx.x>>6);
  int n0 = wid*4;
  if(n0>=N) return;
  int r0 = __builtin_amdgcn_readfirstlane(rowptr[n0]);
  int r1 = __builtin_amdgcn_readfirstlane(rowptr[min(n0+1,N)]);
  int r2 = __builtin_amdgcn_readfirstlane(rowptr[min(n0+2,N)]);
  int r3 = __builtin_amdgcn_readfirstlane(rowptr[min(n0+3,N)]);
  int r4 = __builtin_amdgcn_readfirstlane(rowptr[min(n0+4,N)]);
  float ar0=0.f,ai0=0.f, ar1=0.f,ai1=0.f, ar2=0.f,ai2=0.f, ar3=0.f,ai3=0.f;

#define SELADD(J, car, cai)                          \
  if((J)<r1)      { ar0+=car; ai0+=cai; }            \
  else if((J)<r2) { ar1+=car; ai1+=cai; }            \
  else if((J)<r3) { ar2+=car; ai2+=cai; }            \
  else            { ar3+=car; ai3+=cai; }

#define BLK4(Q0,Q1,Q2,Q3,V0,V1,V2,V3,J)                               \
  {                                                                   \
    float2 e0=__half22float2(*(const __half2*)&Q0.y);                 \
    float2 e1=__half22float2(*(const __half2*)&Q1.y);                 \
    float2 e2=__half22float2(*(const __half2*)&Q2.y);                 \
    float2 e3=__half22float2(*(const __half2*)&Q3.y);                 \
    float cr0, ci0, cr1, ci1;                                         \
    cr0 = e0.x*V0.x;             cr0 = fmaf(-e0.y, V0.y, cr0);        \
    ci0 = e0.y*V0.x;             ci0 = fmaf( e0.x, V0.y, ci0);        \
    cr1 = e1.x*V1.x;             cr1 = fmaf(-e1.y, V1.y, cr1);        \
    ci1 = e1.y*V1.x;             ci1 = fmaf( e1.x, V1.y, ci1);        \
    cr0 = fmaf(e2.x, V2.x, cr0); cr0 = fmaf(-e2.y, V2.y, cr0);        \
    ci0 = fmaf(e2.y, V2.x, ci0); ci0 = fmaf( e2.x, V2.y, ci0);        \
    cr1 = fmaf(e3.x, V3.x, cr1); cr1 = fmaf(-e3.y, V3.y, cr1);        \
    ci1 = fmaf(e3.y, V3.x, ci1); ci1 = fmaf( e3.x, V3.y, ci1);        \
    float car = cr0 + cr1, cai = ci0 + ci1;                           \
    SELADD(J, car, cai);                                              \
  }

  int jb = r0;
  for(; jb+8<=r4; jb+=8){
    uint2 qa0=eS[jb  ], qa1=eS[jb+1], qa2=eS[jb+2], qa3=eS[jb+3];
    uint2 qb0=eS[jb+4], qb1=eS[jb+5], qb2=eS[jb+6], qb3=eS[jb+7];
    float2 va0=__half22float2(hrhi[(int)qa0.x*HID+lane]);
    float2 va1=__half22float2(hrhi[(int)qa1.x*HID+lane]);
    float2 va2=__half22float2(hrhi[(int)qa2.x*HID+lane]);
    float2 va3=__half22float2(hrhi[(int)qa3.x*HID+lane]);
    float2 vb0=__half22float2(hrhi[(int)qb0.x*HID+lane]);
    float2 vb1=__half22float2(hrhi[(int)qb1.x*HID+lane]);
    float2 vb2=__half22float2(hrhi[(int)qb2.x*HID+lane]);
    float2 vb3=__half22float2(hrhi[(int)qb3.x*HID+lane]);
    BLK4(qa0,qa1,qa2,qa3, va0,va1,va2,va3, jb);
    BLK4(qb0,qb1,qb2,qb3, vb0,vb1,vb2,vb3, jb+4);
  }
  if(jb<r4){
    uint2 q0=eS[jb], q1=eS[jb+1], q2=eS[jb+2], q3=eS[jb+3];
    float2 v0=__half22float2(hrhi[(int)q0.x*HID+lane]);
    float2 v1=__half22float2(hrhi[(int)q1.x*HID+lane]);
    float2 v2=__half22float2(hrhi[(int)q2.x*HID+lane]);
    float2 v3=__half22float2(hrhi[(int)q3.x*HID+lane]);
    BLK4(q0,q1,q2,q3, v0,v1,v2,v3, jb);
  }
#undef BLK4
#undef SELADD

  if(n0+0<N) *(float2*)&zrzi[((n0+0)*HID+lane)*2] = make_float2(ar0, ai0);
  if(n0+1<N) *(float2*)&zrzi[((n0+1)*HID+lane)*2] = make_float2(ar1, ai1);
  if(n0+2<N) *(float2*)&zrzi[((n0+2)*HID+lane)*2] = make_float2(ar2, ai2);
  if(n0+3<N) *(float2*)&zrzi[((n0+3)*HID+lane)*2] = make_float2(ar3, ai3);
}

// fused complex dense layer; fp16 LDS + fdot2, merged A/B/C pass.
// When last!=0: instead of writing hrhi, computes logits + log_softmax for the
// block's 64 nodes (k_final fused in; t2W read through L1, 4 KB).
__global__ __launch_bounds__(256, 4) void k_dense(
    const float* __restrict__ W1, const float* __restrict__ b1,
    const float* __restrict__ W2, const float* __restrict__ b2,
    const float* __restrict__ zrzi, __half2* __restrict__ hrhi, int N,
    const float* __restrict__ t2W, const float* __restrict__ t2b,
    float* __restrict__ out, int last){
  __shared__ __align__(16) __half sW1h[64*HPAD], sW2h[64*HPAD];
  __shared__ __align__(16) __half sZRh[TN*HPAD], sZIh[TN*HPAD];
  int tid = threadIdx.x;
  int o = tid & 15, grp = tid >> 4;
  int node0 = blockIdx.x*TN;
  #pragma unroll
  for(int t=0;t<4;t++){
    int f4 = tid + t*256; int row = f4>>4, kc = f4&15;
    *(uint2*)&sW1h[row*HPAD + kc*4] = pack4(*(const float4*)&W1[row*HID + kc*4]);
    *(uint2*)&sW2h[row*HPAD + kc*4] = pack4(*(const float4*)&W2[row*HID + kc*4]);
  }
  #pragma unroll
  for(int t=0;t<8;t++){
    int f4 = tid + t*256;         // 0..2047 over 64 nodes x 32 quads
    int nl = f4 >> 5, q = f4 & 31;
    int node = node0 + nl;
    float4 v = make_float4(0.f,0.f,0.f,0.f);
    if(node<N) v = *(const float4*)&zrzi[node*(2*HID) + q*4];
    __half2 zr2 = __floats2half2_rn(v.x, v.z);
    __half2 zi2 = __floats2half2_rn(v.y, v.w);
    *(unsigned*)&sZRh[nl*HPAD + q*2] = *(unsigned*)&zr2;
    *(unsigned*)&sZIh[nl*HPAD + q*2] = *(unsigned*)&zi2;
  }
  __syncthreads();

  float b1v[4], b2v[4];
  #pragma unroll
  for(int r=0;r<4;r++){ b1v[r]=b1[o+16*r]; b2v[r]=b2[o+16*r]; }

  // merged pass A/B/C: accA = zr.W1, accB = zi.W2, accC = zi.W1
  float zrn[4][4], accC[4][4];
  {
    float accA[4][4], accB[4][4];
    #pragma unroll
    for(int r=0;r<4;r++)
      #pragma unroll
      for(int m=0;m<4;m++){ accA[r][m]=0.f; accB[r][m]=0.f; accC[r][m]=0.f; }
    #pragma unroll 2
    for(int c=0;c<8;c++){
      uint4 w1v[4], w2v[4];
      #pragma unroll
      for(int r=0;r<4;r++){
        w1v[r] = *(const uint4*)&sW1h[(o+16*r)*HPAD + c*8];
        w2v[r] = *(const uint4*)&sW2h[(o+16*r)*HPAD + c*8];
      }
      #pragma unroll
      for(int m=0;m<4;m++){
        uint4 xr = *(const uint4*)&sZRh[(grp*4+m)*HPAD + c*8];
        uint4 xi = *(const uint4*)&sZIh[(grp*4+m)*HPAD + c*8];
        #pragma unroll
        for(int r=0;r<4;r++){
          accA[r][m] = dot8h(xr, w1v[r], accA[r][m]);
          accB[r][m] = dot8h(xi, w2v[r], accB[r][m]);
          accC[r][m] = dot8h(xi, w1v[r], accC[r][m]);
        }
      }
    }
    #pragma unroll
    for(int r=0;r<4;r++)
      #pragma unroll
      for(int m=0;m<4;m++)
        zrn[r][m] = accA[r][m] + b1v[r] - accB[r][m] - b2v[r];
  }
  __syncthreads();                 // all reads of sZRh done
  #pragma unroll
  for(int m=0;m<4;m++)
    #pragma unroll
    for(int r=0;r<4;r++)
      sZRh[(grp*4+m)*HPAD + o + 16*r] = __float2half(zrn[r][m]); // pre-relu zrn
  __syncthreads();
  // pass D: accD = zrn . W2
  float accD[4][4];
  #pragma unroll
  for(int r=0;r<4;r++)
    #pragma unroll
    for(int m=0;m<4;m++) accD[r][m]=0.f;
  #pragma unroll 2
  for(int c=0;c<8;c++){
    uint4 w2v[4];
    #pragma unroll
    for(int r=0;r<4;r++)
      w2v[r] = *(const uint4*)&sW2h[(o+16*r)*HPAD + c*8];
    #pragma unroll
    for(int m=0;m<4;m++){
      uint4 x = *(const uint4*)&sZRh[(grp*4+m)*HPAD + c*8];
      #pragma unroll
      for(int r=0;r<4;r++)
        accD[r][m] = dot8h(x, w2v[r], accD[r][m]);
    }
  }

  if(!last){
    #pragma unroll
    for(int m=0;m<4;m++){
      int node = node0 + grp*4 + m;
      if(node<N){
        #pragma unroll
        for(int r=0;r<4;r++){
          float zin = accD[r][m] + b2v[r] + accC[r][m] + b1v[r];
          hrhi[node*HID + o + 16*r] =
            __floats2half2_rn(fmaxf(zrn[r][m],0.f), fmaxf(zin,0.f));
        }
      }
    }
    return;
  }

  // ---- fused final head: relu'd tile to LDS, logits + log_softmax ----
  __syncthreads();                 // drain pass-D reads before overwriting LDS
  #pragma unroll
  for(int m=0;m<4;m++)
    #pragma unroll
    for(int r=0;r<4;r++){
      float zin = accD[r][m] + b2v[r] + accC[r][m] + b1v[r];
      sZRh[(grp*4+m)*HPAD + o + 16*r] = __float2half(fmaxf(zrn[r][m],0.f));
      sZIh[(grp*4+m)*HPAD + o + 16*r] = __float2half(fmaxf(zin,0.f));
    }
  __syncthreads();
  {
    int node = tid >> 2, pair = tid & 3;     // 64 nodes x 4 threads (2 logits each)
    int gnode = node0 + node;
    float acc0 = t2b[2*pair], acc1 = t2b[2*pair+1];
    const float4* w0p = (const float4*)&t2W[(2*pair)*128];
    const float4* w1p = (const float4*)&t2W[(2*pair+1)*128];
    #pragma unroll
    for(int c=0;c<8;c++){
      uint4 xr = *(const uint4*)&sZRh[node*HPAD + c*8];
      uint4 xi = *(const uint4*)&sZIh[node*HPAD + c*8];
      float2 a0=__half22float2(*(__half2*)&xr.x), a1=__half22float2(*(__half2*)&xr.y);
      float2 a2=__half22float2(*(__half2*)&xr.z), a3=__half22float2(*(__half2*)&xr.w);
      float2 g0=__half22float2(*(__half2*)&xi.x), g1=__half22float2(*(__half2*)&xi.y);
      float2 g2=__half22float2(*(__half2*)&xi.z), g3=__half22float2(*(__half2*)&xi.w);
      float4 fr0 = make_float4(a0.x,a0.y,a1.x,a1.y);
      float4 fr1 = make_float4(a2.x,a2.y,a3.x,a3.y);
      float4 fi0 = make_float4(g0.x,g0.y,g1.x,g1.y);
      float4 fi1 = make_float4(g2.x,g2.y,g3.x,g3.y);
      acc0 += dot4(fr0, w0p[2*c]) + dot4(fr1, w0p[2*c+1]);
      acc0 += dot4(fi0, w0p[16+2*c]) + dot4(fi1, w0p[16+2*c+1]);
      acc1 += dot4(fr0, w1p[2*c]) + dot4(fr1, w1p[2*c+1]);
      acc1 += dot4(fi0, w1p[16+2*c]) + dot4(fi1, w1p[16+2*c+1]);
    }
    float mx = fmaxf(acc0, acc1);
    mx = fmaxf(mx, __shfl_xor(mx, 1, 4));
    mx = fmaxf(mx, __shfl_xor(mx, 2, 4));
    float sm = expf(acc0-mx) + expf(acc1-mx);
    sm += __shfl_xor(sm, 1, 4);
    sm += __shfl_xor(sm, 2, 4);
    float ls = logf(sm);
    if(gnode<N){
      out[gnode*OUTC + 2*pair]     = acc0 - mx - ls;
      out[gnode*OUTC + 2*pair + 1] = acc1 - mx - ls;
    }
  }
}

extern "C" void kernel_launch(void* const* d_in, const int* in_sizes, int n_in,
                              void* d_out, int out_size, void* d_ws, size_t ws_size,
                              hipStream_t stream) {
  const float* h      = (const float*)d_in[0];
  const float* d      = (const float*)d_in[1];
  const float* w_real = (const float*)d_in[2];
  const float* w_imag = (const float*)d_in[3];
  const float* t1rW   = (const float*)d_in[4];
  const float* t1rb   = (const float*)d_in[5];
  const float* t1iW   = (const float*)d_in[6];
  const float* t1ib   = (const float*)d_in[7];
  const float* W1     = (const float*)d_in[8];
  const float* b1     = (const float*)d_in[9];
  const float* W2     = (const float*)d_in[10];
  const float* b2     = (const float*)d_in[11];
  const float* t2W    = (const float*)d_in[12];
  const float* t2b    = (const float*)d_in[13];
  const int*   src    = (const int*)d_in[14];
  const int*   dst    = (const int*)d_in[15];
  int N = in_sizes[1];
  int E = in_sizes[2];
  const int nLayers = in_sizes[8] / (HID*HID);
  float* out = (float*)d_out;

  char* w = (char*)d_ws;
  size_t off = 0;
  auto alloc = [&](size_t bytes)->void*{
    void* p = (void*)(w + off);
    off += (bytes + 255) & ~(size_t)255;
    return p;
  };
  __half2* hrhi   = (__half2*)alloc((size_t)N*HID*sizeof(__half2));
  float*  zrzi    = (float*)alloc((size_t)N*2*HID*4);
  int*    rowptr  = (int*)alloc((size_t)(N+1)*4);
  int*    cnt     = (int*)alloc((size_t)N*4);
  int*    rank    = (int*)alloc((size_t)E*4);
  uint2*  eS      = (uint2*)alloc(((size_t)E + 3*(size_t)N + 8)*8);
  int*    partials= (int*)alloc(2048);

  int nChunks = (N+255)/256;
  int nTiles  = (N+TN-1)/TN;
  int aggWaves  = (N+3)/4;
  int aggBlocks = (aggWaves+3)/4;

  // single cooperative dispatch for the whole CSR build
  {
    void* args[] = { (void*)&src, (void*)&dst, (void*)&d, (void*)&w_real,
                     (void*)&w_imag, (void*)&cnt, (void*)&rank, (void*)&rowptr,
                     (void*)&partials, (void*)&eS, (void*)&N, (void*)&E,
                     (void*)&nChunks };
    hipLaunchCooperativeKernel((const void*)k_build, dim3(256), dim3(256),
                               args, 0, stream);
  }

  k_transform1<<<nTiles, 256, 0, stream>>>(h, t1rW, t1rb, t1iW, t1ib, hrhi, N);
  for(int i=0;i<nLayers;i++){
    k_agg<<<aggBlocks, 256, 0, stream>>>(rowptr, eS, hrhi, zrzi, N);
    k_dense<<<nTiles, 256, 0, stream>>>(W1 + (size_t)i*HID*HID, b1 + (size_t)i*HID,
                                        W2 + (size_t)i*HID*HID, b2 + (size_t)i*HID,
                                        zrzi, hrhi, N,
                                        t2W, t2b, out, (i==nLayers-1)?1:0);
  }
}